// Round 1
// baseline (301.513 us; speedup 1.0000x reference)
//
#include <hip/hip_runtime.h>
#include <hip/hip_bf16.h>

// IsolaCLIPLoss: out = 3*align + 0.5*(log-mean-exp uniformity of img Gram + txt Gram)
// N=8192, D=512 fp32 inputs.
//
// Pipeline:
//   1) normalize_kernel: row L2-normalize both inputs, emit bf16 copies to ws,
//      and accumulate sum_i dot(nimg_i, ntxt_i) for the align loss.
//   2) gram_kernel (x2 via gridDim.y): upper-triangular 128x128 tiles of G=A*A^T
//      via bf16 MFMA; epilogue applies exp(4*min(G,1)-4) and block-reduces into
//      a scalar accumulator (off-diag tiles weighted 2x by symmetry).
//   3) finalize_kernel: scalar combine.

#define NROWS 8192
#define DDIM  512
#define NT    64           // 8192/128 tiles per dim
#define NTILES 2080        // NT*(NT+1)/2 upper-triangular tiles

typedef __attribute__((ext_vector_type(8))) short short8;   // 8 x bf16 = 4 VGPRs
typedef __attribute__((ext_vector_type(4))) float float4v;  // MFMA C/D

__device__ inline void load_lds16(const void* g, void* l) {
    __builtin_amdgcn_global_load_lds(
        (const __attribute__((address_space(1))) void*)g,
        (__attribute__((address_space(3))) void*)l, 16, 0, 0);
}

// ---------------------------------------------------------------- normalize
__global__ __launch_bounds__(512) void normalize_kernel(
    const float* __restrict__ img, const float* __restrict__ txt,
    __hip_bfloat16* __restrict__ nimg, __hip_bfloat16* __restrict__ ntxt,
    float* __restrict__ acc)   // acc[0] += sum_i ndot_i
{
    const int row = blockIdx.x;
    const int c   = threadIdx.x;          // 0..511, one element each
    const float xi = img[(size_t)row * DDIM + c];
    const float xt = txt[(size_t)row * DDIM + c];
    float ssi = xi * xi, sst = xt * xt, dot = xi * xt;
    #pragma unroll
    for (int off = 32; off; off >>= 1) {
        ssi += __shfl_down(ssi, off);
        sst += __shfl_down(sst, off);
        dot += __shfl_down(dot, off);
    }
    __shared__ float r[3][8];
    const int wave = c >> 6, lane = c & 63;
    if (lane == 0) { r[0][wave] = ssi; r[1][wave] = sst; r[2][wave] = dot; }
    __syncthreads();
    if (c == 0) {
        float a = 0.f, b = 0.f, d = 0.f;
        #pragma unroll
        for (int w = 0; w < 8; ++w) { a += r[0][w]; b += r[1][w]; d += r[2][w]; }
        r[0][0] = a; r[1][0] = b; r[2][0] = d;
    }
    __syncthreads();
    const float inv_i = 1.0f / fmaxf(sqrtf(r[0][0]), 1e-12f);
    const float inv_t = 1.0f / fmaxf(sqrtf(r[1][0]), 1e-12f);
    nimg[(size_t)row * DDIM + c] = __float2bfloat16(xi * inv_i);
    ntxt[(size_t)row * DDIM + c] = __float2bfloat16(xt * inv_t);
    if (c == 0) atomicAdd(&acc[0], r[2][0] * inv_i * inv_t);
}

// ---------------------------------------------------------------- gram + lme
// 128x128 tile per block, 4 waves in 2x2, each wave 4x4 grid of 16x16x32 MFMA.
__global__ __launch_bounds__(256) void gram_kernel(
    const short* __restrict__ A0,   // bf16-as-short, [8192][512], blockIdx.y==0
    const short* __restrict__ A1,   // blockIdx.y==1
    float* __restrict__ S)          // S[blockIdx.y] += weighted tile exp-sum
{
    // Decode upper-triangular tile index t -> (i, j), i <= j.
    // off(i) = #tiles with row < i = i*(129-i)/2
    const int t = blockIdx.x;
    int i = (int)((129.0f - sqrtf(129.0f * 129.0f - 8.0f * (float)t)) * 0.5f);
    while ((i + 1) * (129 - (i + 1)) / 2 <= t) ++i;
    while (i * (129 - i) / 2 > t) --i;
    const int j = i + (t - i * (129 - i) / 2);

    const short* __restrict__ A = blockIdx.y ? A1 : A0;
    const int tid  = threadIdx.x;
    const int lane = tid & 63;
    const int wave = tid >> 6;
    const int wm = wave & 1, wn = wave >> 1;   // 2x2 wave grid over 128x128

    const short* gA = A + (size_t)i * 128 * DDIM;
    const short* gB = A + (size_t)j * 128 * DDIM;

    __shared__ __align__(16) short ldsA[128 * 64];   // 16 KB
    __shared__ __align__(16) short ldsB[128 * 64];   // 16 KB

    float4v acc[4][4];
    const float4v zero = {0.f, 0.f, 0.f, 0.f};
    #pragma unroll
    for (int a = 0; a < 4; ++a)
        #pragma unroll
        for (int b = 0; b < 4; ++b) acc[a][b] = zero;

    for (int k0 = 0; k0 < DDIM; k0 += 64) {
        // Stage 128x64 bf16 tiles of A-rows and B-rows (NT layout: both
        // operands read contiguous along K). 256 thr * 8 elem * 4 rounds.
        #pragma unroll
        for (int rnd = 0; rnd < 4; ++rnd) {
            const int e = rnd * 2048 + tid * 8;   // elem idx in [128][64] tile
            const int r = e >> 6, c = e & 63;
            load_lds16(gA + (size_t)r * DDIM + k0 + c, &ldsA[e]);
            load_lds16(gB + (size_t)r * DDIM + k0 + c, &ldsB[e]);
        }
        __syncthreads();

        #pragma unroll
        for (int kk = 0; kk < 64; kk += 32) {
            short8 af[4], bf[4];
            const int mrow = wm * 64 + (lane & 15);
            const int nrow = wn * 64 + (lane & 15);
            const int kq = kk + ((lane >> 4) << 3);
            #pragma unroll
            for (int mt = 0; mt < 4; ++mt)
                af[mt] = *(const short8*)&ldsA[(mrow + mt * 16) * 64 + kq];
            #pragma unroll
            for (int nt = 0; nt < 4; ++nt)
                bf[nt] = *(const short8*)&ldsB[(nrow + nt * 16) * 64 + kq];
            #pragma unroll
            for (int mt = 0; mt < 4; ++mt)
                #pragma unroll
                for (int nt = 0; nt < 4; ++nt)
                    acc[mt][nt] = __builtin_amdgcn_mfma_f32_16x16x32_bf16(
                        af[mt], bf[nt], acc[mt][nt], 0, 0, 0);
        }
        __syncthreads();
    }

    // Epilogue: exp(4*min(G,1)-4) over all 64 per-lane values, reduce, atomic.
    float s = 0.0f;
    #pragma unroll
    for (int mt = 0; mt < 4; ++mt)
        #pragma unroll
        for (int nt = 0; nt < 4; ++nt)
            #pragma unroll
            for (int r2 = 0; r2 < 4; ++r2) {
                const float g = acc[mt][nt][r2];
                s += __expf(4.0f * fminf(g, 1.0f) - 4.0f);
            }
    #pragma unroll
    for (int off = 32; off; off >>= 1) s += __shfl_down(s, off);
    __shared__ float ps[4];
    if (lane == 0) ps[wave] = s;
    __syncthreads();
    if (tid == 0) {
        const float tot = ps[0] + ps[1] + ps[2] + ps[3];
        const float w = (i == j) ? 1.0f : 2.0f;   // symmetry weight
        atomicAdd(&S[blockIdx.y], tot * w);
    }
}

// ---------------------------------------------------------------- finalize
__global__ void finalize_kernel(const float* __restrict__ acc, float* __restrict__ out)
{
    const double align = 2.0 - 2.0 * (double)acc[0] / (double)NROWS;
    const double n2 = (double)NROWS * (double)NROWS;
    const double unif = 0.5 * (log((double)acc[1] / n2) + log((double)acc[2] / n2));
    out[0] = (float)(3.0 * align + unif);
}

// ---------------------------------------------------------------- launch
extern "C" void kernel_launch(void* const* d_in, const int* in_sizes, int n_in,
                              void* d_out, int out_size, void* d_ws, size_t ws_size,
                              hipStream_t stream) {
    const float* img = (const float*)d_in[0];
    const float* txt = (const float*)d_in[1];
    char* ws = (char*)d_ws;
    __hip_bfloat16* nimg = (__hip_bfloat16*)ws;                                  // 8 MB
    __hip_bfloat16* ntxt = (__hip_bfloat16*)(ws + (size_t)NROWS * DDIM * 2);     // 8 MB
    float* acc = (float*)(ws + (size_t)NROWS * DDIM * 4);  // [0]=align dot, [1]=S_img, [2]=S_txt

    hipMemsetAsync(acc, 0, 3 * sizeof(float), stream);
    normalize_kernel<<<NROWS, 512, 0, stream>>>(img, txt, nimg, ntxt, acc);
    dim3 grid(NTILES, 2);
    gram_kernel<<<grid, 256, 0, stream>>>((const short*)nimg, (const short*)ntxt, &acc[1]);
    finalize_kernel<<<1, 1, 0, stream>>>(acc, (float*)d_out);
}

// Round 2
// 212.589 us; speedup vs baseline: 1.4183x; 1.4183x over previous
//
#include <hip/hip_runtime.h>
#include <hip/hip_bf16.h>

// IsolaCLIPLoss: out = 3*align + 0.5*(log-mean-exp uniformity of img Gram + txt Gram)
// N=8192, D=512 fp32 inputs.
//
// R2 changes vs R1:
//  - gram: XOR-swizzled LDS layout (chunk ^= row&7) kills the 16-way bank
//    conflict on fragment ds_read_b128 (was 2.56e7 conflict cycles/dispatch).
//  - normalize: wave-per-row, float4 loads, butterfly shuffle reduce, vector
//    bf16 stores, 1 atomic/wave (was: scalar loads + 8192 same-addr atomics).

#define NROWS 8192
#define DDIM  512
#define NT    64           // 8192/128 tiles per dim
#define NTILES 2080        // NT*(NT+1)/2 upper-triangular tiles

typedef __attribute__((ext_vector_type(8))) short short8;   // 8 x bf16 = 4 VGPRs
typedef __attribute__((ext_vector_type(4))) float float4v;  // MFMA C/D
typedef __attribute__((ext_vector_type(4))) unsigned short ushort4v;

__device__ inline void load_lds16(const void* g, void* l) {
    __builtin_amdgcn_global_load_lds(
        (const __attribute__((address_space(1))) void*)g,
        (__attribute__((address_space(3))) void*)l, 16, 0, 0);
}

__device__ inline unsigned short f2bf(float x) {
    __hip_bfloat16 h = __float2bfloat16(x);
    return *(unsigned short*)&h;
}

// ---------------------------------------------------------------- normalize
// One wave per row (grid-stride). Lane covers cols [4L,4L+4) and [256+4L,..).
__global__ __launch_bounds__(256) void normalize_kernel(
    const float* __restrict__ img, const float* __restrict__ txt,
    unsigned short* __restrict__ nimg, unsigned short* __restrict__ ntxt,
    float* __restrict__ acc)   // acc[0] += sum_i dot(nimg_i, ntxt_i)
{
    const int lane = threadIdx.x & 63;
    const int wid  = (blockIdx.x * 256 + threadIdx.x) >> 6;   // 0..2047
    float align_acc = 0.0f;

    for (int row = wid; row < NROWS; row += 2048) {
        const float4* pi = (const float4*)(img + (size_t)row * DDIM);
        const float4* pt = (const float4*)(txt + (size_t)row * DDIM);
        const float4 i0 = pi[lane], i1 = pi[lane + 64];
        const float4 t0 = pt[lane], t1 = pt[lane + 64];

        float ssi = i0.x*i0.x + i0.y*i0.y + i0.z*i0.z + i0.w*i0.w
                  + i1.x*i1.x + i1.y*i1.y + i1.z*i1.z + i1.w*i1.w;
        float sst = t0.x*t0.x + t0.y*t0.y + t0.z*t0.z + t0.w*t0.w
                  + t1.x*t1.x + t1.y*t1.y + t1.z*t1.z + t1.w*t1.w;
        float dot = i0.x*t0.x + i0.y*t0.y + i0.z*t0.z + i0.w*t0.w
                  + i1.x*t1.x + i1.y*t1.y + i1.z*t1.z + i1.w*t1.w;

        #pragma unroll
        for (int off = 1; off < 64; off <<= 1) {
            ssi += __shfl_xor(ssi, off);
            sst += __shfl_xor(sst, off);
            dot += __shfl_xor(dot, off);
        }
        const float inv_i = 1.0f / fmaxf(sqrtf(ssi), 1e-12f);
        const float inv_t = 1.0f / fmaxf(sqrtf(sst), 1e-12f);

        ushort4v vi0, vi1, vt0, vt1;
        vi0[0] = f2bf(i0.x * inv_i); vi0[1] = f2bf(i0.y * inv_i);
        vi0[2] = f2bf(i0.z * inv_i); vi0[3] = f2bf(i0.w * inv_i);
        vi1[0] = f2bf(i1.x * inv_i); vi1[1] = f2bf(i1.y * inv_i);
        vi1[2] = f2bf(i1.z * inv_i); vi1[3] = f2bf(i1.w * inv_i);
        vt0[0] = f2bf(t0.x * inv_t); vt0[1] = f2bf(t0.y * inv_t);
        vt0[2] = f2bf(t0.z * inv_t); vt0[3] = f2bf(t0.w * inv_t);
        vt1[0] = f2bf(t1.x * inv_t); vt1[1] = f2bf(t1.y * inv_t);
        vt1[2] = f2bf(t1.z * inv_t); vt1[3] = f2bf(t1.w * inv_t);

        ushort4v* oi = (ushort4v*)(nimg + (size_t)row * DDIM);
        ushort4v* ot = (ushort4v*)(ntxt + (size_t)row * DDIM);
        oi[lane] = vi0; oi[lane + 64] = vi1;
        ot[lane] = vt0; ot[lane + 64] = vt1;

        if (lane == 0) align_acc += dot * inv_i * inv_t;
    }
    if (lane == 0) atomicAdd(&acc[0], align_acc);
}

// ---------------------------------------------------------------- gram + lme
// 128x128 tile per block, 4 waves in 2x2, each wave 4x4 grid of 16x16x32 MFMA.
// LDS tiles are [128 rows][8 chunks of 8 bf16], physical chunk = chunk^(row&7).
__global__ __launch_bounds__(256) void gram_kernel(
    const short* __restrict__ A0,   // bf16-as-short, [8192][512], blockIdx.y==0
    const short* __restrict__ A1,   // blockIdx.y==1
    float* __restrict__ S)          // S[blockIdx.y] += weighted tile exp-sum
{
    // Decode upper-triangular tile index t -> (i, j), i <= j.
    const int t = blockIdx.x;
    int i = (int)((129.0f - sqrtf(129.0f * 129.0f - 8.0f * (float)t)) * 0.5f);
    while ((i + 1) * (129 - (i + 1)) / 2 <= t) ++i;
    while (i * (129 - i) / 2 > t) --i;
    const int j = i + (t - i * (129 - i) / 2);

    const short* __restrict__ A = blockIdx.y ? A1 : A0;
    const int tid  = threadIdx.x;
    const int lane = tid & 63;
    const int wave = tid >> 6;
    const int wm = wave & 1, wn = wave >> 1;   // 2x2 wave grid over 128x128

    const short* gA = A + (size_t)i * 128 * DDIM;
    const short* gB = A + (size_t)j * 128 * DDIM;

    __shared__ __align__(16) short ldsA[128 * 64];   // 16 KB
    __shared__ __align__(16) short ldsB[128 * 64];   // 16 KB

    float4v acc[4][4];
    const float4v zero = {0.f, 0.f, 0.f, 0.f};
    #pragma unroll
    for (int a = 0; a < 4; ++a)
        #pragma unroll
        for (int b = 0; b < 4; ++b) acc[a][b] = zero;

    for (int k0 = 0; k0 < DDIM; k0 += 64) {
        // Stage 128x64 bf16 tiles. LDS slot is lane-contiguous (required by
        // global_load_lds); the GLOBAL chunk fetched into slot (r, c) is
        // c ^ (r&7)  -> XOR-swizzled LDS layout, global stays 128B-coalesced.
        #pragma unroll
        for (int rnd = 0; rnd < 4; ++rnd) {
            const int slot  = rnd * 2048 + tid * 8;   // element idx in tile
            const int r     = slot >> 6;
            const int chunk = (slot >> 3) & 7;
            const int gc    = chunk ^ (r & 7);
            load_lds16(gA + (size_t)r * DDIM + k0 + gc * 8, &ldsA[slot]);
            load_lds16(gB + (size_t)r * DDIM + k0 + gc * 8, &ldsB[slot]);
        }
        __syncthreads();

        #pragma unroll
        for (int kk = 0; kk < 64; kk += 32) {
            short8 af[4], bf[4];
            const int mrow = wm * 64 + (lane & 15);
            const int nrow = wn * 64 + (lane & 15);
            const int kch  = (kk >> 3) + (lane >> 4);     // logical chunk
            const int sw   = lane & 7;                    // (row&7) for all mt
            #pragma unroll
            for (int mt = 0; mt < 4; ++mt)
                af[mt] = *(const short8*)&ldsA[(mrow + mt * 16) * 64 + ((kch ^ sw) << 3)];
            #pragma unroll
            for (int nt = 0; nt < 4; ++nt)
                bf[nt] = *(const short8*)&ldsB[(nrow + nt * 16) * 64 + ((kch ^ sw) << 3)];
            #pragma unroll
            for (int mt = 0; mt < 4; ++mt)
                #pragma unroll
                for (int nt = 0; nt < 4; ++nt)
                    acc[mt][nt] = __builtin_amdgcn_mfma_f32_16x16x32_bf16(
                        af[mt], bf[nt], acc[mt][nt], 0, 0, 0);
        }
        __syncthreads();
    }

    // Epilogue: exp(4*min(G,1)-4) over all per-lane values, reduce, atomic.
    float s = 0.0f;
    #pragma unroll
    for (int mt = 0; mt < 4; ++mt)
        #pragma unroll
        for (int nt = 0; nt < 4; ++nt)
            #pragma unroll
            for (int r2 = 0; r2 < 4; ++r2) {
                const float g = acc[mt][nt][r2];
                s += __expf(4.0f * fminf(g, 1.0f) - 4.0f);
            }
    #pragma unroll
    for (int off = 32; off; off >>= 1) s += __shfl_down(s, off);
    __shared__ float ps[4];
    if (lane == 0) ps[wave] = s;
    __syncthreads();
    if (tid == 0) {
        const float tot = ps[0] + ps[1] + ps[2] + ps[3];
        const float w = (i == j) ? 1.0f : 2.0f;   // symmetry weight
        atomicAdd(&S[blockIdx.y], tot * w);
    }
}

// ---------------------------------------------------------------- finalize
__global__ void finalize_kernel(const float* __restrict__ acc, float* __restrict__ out)
{
    const double align = 2.0 - 2.0 * (double)acc[0] / (double)NROWS;
    const double n2 = (double)NROWS * (double)NROWS;
    const double unif = 0.5 * (log((double)acc[1] / n2) + log((double)acc[2] / n2));
    out[0] = (float)(3.0 * align + unif);
}

// ---------------------------------------------------------------- launch
extern "C" void kernel_launch(void* const* d_in, const int* in_sizes, int n_in,
                              void* d_out, int out_size, void* d_ws, size_t ws_size,
                              hipStream_t stream) {
    const float* img = (const float*)d_in[0];
    const float* txt = (const float*)d_in[1];
    char* ws = (char*)d_ws;
    unsigned short* nimg = (unsigned short*)ws;                                  // 8 MB
    unsigned short* ntxt = (unsigned short*)(ws + (size_t)NROWS * DDIM * 2);     // 8 MB
    float* acc = (float*)(ws + (size_t)NROWS * DDIM * 4);  // [0]=align dot, [1]=S_img, [2]=S_txt

    hipMemsetAsync(acc, 0, 3 * sizeof(float), stream);
    normalize_kernel<<<512, 256, 0, stream>>>(img, txt, nimg, ntxt, acc);
    dim3 grid(NTILES, 2);
    gram_kernel<<<grid, 256, 0, stream>>>((const short*)nimg, (const short*)ntxt, &acc[1]);
    finalize_kernel<<<1, 1, 0, stream>>>(acc, (float*)d_out);
}

// Round 3
// 129.163 us; speedup vs baseline: 2.3344x; 1.6459x over previous
//
#include <hip/hip_runtime.h>
#include <hip/hip_bf16.h>

// IsolaCLIPLoss: out = 3*align + 0.5*(log-mean-exp uniformity of img Gram + txt Gram)
// N=8192, D=512 fp32 inputs.
//
// R3 changes vs R2:
//  - gram: MX-fp8 path. Rows quantized to e4m3 * 2^10; MFMA =
//    mfma_scale_f32_32x32x64_f8f6f4 with E8M0 scale 2^-10 per operand
//    (exact pow2 -> no extra error vs plain fp8). Halves staging bytes and
//    doubles MFMA rate vs bf16. BK=128 (4 K-iters, 8 barriers/block).
//  - LDS swizzle chunk^=(row&7) keeps fragment ds_read_b128 conflict-free.
//  - no same-address atomics: per-block align partials + 32-way-spread gram
//    accumulators, reduced in finalize.

#define NROWS 8192
#define DBYTES 512         // row stride in bytes (fp8) == D
#define NT    64           // 8192/128 tiles per dim
#define NTILES 2080        // NT*(NT+1)/2 upper-triangular tiles
#define SCALE_SPLAT 0x75757575  // E8M0 byte 117 = 2^-10, splatted

typedef __attribute__((ext_vector_type(8)))  int   int8v;
typedef __attribute__((ext_vector_type(4)))  int   int4v;
typedef __attribute__((ext_vector_type(16))) float float16v;

__device__ inline void load_lds16(const void* g, void* l) {
    __builtin_amdgcn_global_load_lds(
        (const __attribute__((address_space(1))) void*)g,
        (__attribute__((address_space(3))) void*)l, 16, 0, 0);
}

// ---------------------------------------------------------------- normalize
// 4 rows per block (one per wave). fp32 float4 loads, shuffle reduce,
// quantize to e4m3 * 2^10, 4B int stores. Align partial per block (no atomics).
__global__ __launch_bounds__(256) void normalize_kernel(
    const float* __restrict__ img, const float* __restrict__ txt,
    unsigned char* __restrict__ nimg, unsigned char* __restrict__ ntxt,
    float* __restrict__ alignp)   // [2048] per-block partial of sum_i ndot_i
{
    const int lane = threadIdx.x & 63;
    const int wave = threadIdx.x >> 6;
    const int row  = blockIdx.x * 4 + wave;

    const float4* pi = (const float4*)(img + (size_t)row * 512);
    const float4* pt = (const float4*)(txt + (size_t)row * 512);
    const float4 i0 = pi[lane], i1 = pi[lane + 64];
    const float4 t0 = pt[lane], t1 = pt[lane + 64];

    float ssi = i0.x*i0.x + i0.y*i0.y + i0.z*i0.z + i0.w*i0.w
              + i1.x*i1.x + i1.y*i1.y + i1.z*i1.z + i1.w*i1.w;
    float sst = t0.x*t0.x + t0.y*t0.y + t0.z*t0.z + t0.w*t0.w
              + t1.x*t1.x + t1.y*t1.y + t1.z*t1.z + t1.w*t1.w;
    float dot = i0.x*t0.x + i0.y*t0.y + i0.z*t0.z + i0.w*t0.w
              + i1.x*t1.x + i1.y*t1.y + i1.z*t1.z + i1.w*t1.w;

    #pragma unroll
    for (int off = 1; off < 64; off <<= 1) {
        ssi += __shfl_xor(ssi, off);
        sst += __shfl_xor(sst, off);
        dot += __shfl_xor(dot, off);
    }
    const float inv_i = 1.0f / fmaxf(sqrtf(ssi), 1e-12f);
    const float inv_t = 1.0f / fmaxf(sqrtf(sst), 1e-12f);
    const float si = 1024.0f * inv_i;   // quantize at 2^10 scale
    const float st = 1024.0f * inv_t;

    int p0 = __builtin_amdgcn_cvt_pk_fp8_f32(i0.x*si, i0.y*si, 0, false);
    p0     = __builtin_amdgcn_cvt_pk_fp8_f32(i0.z*si, i0.w*si, p0, true);
    int p1 = __builtin_amdgcn_cvt_pk_fp8_f32(i1.x*si, i1.y*si, 0, false);
    p1     = __builtin_amdgcn_cvt_pk_fp8_f32(i1.z*si, i1.w*si, p1, true);
    int q0 = __builtin_amdgcn_cvt_pk_fp8_f32(t0.x*st, t0.y*st, 0, false);
    q0     = __builtin_amdgcn_cvt_pk_fp8_f32(t0.z*st, t0.w*st, q0, true);
    int q1 = __builtin_amdgcn_cvt_pk_fp8_f32(t1.x*st, t1.y*st, 0, false);
    q1     = __builtin_amdgcn_cvt_pk_fp8_f32(t1.z*st, t1.w*st, q1, true);

    int* oi = (int*)(nimg + (size_t)row * DBYTES);
    int* ot = (int*)(ntxt + (size_t)row * DBYTES);
    oi[lane] = p0; oi[lane + 64] = p1;
    ot[lane] = q0; ot[lane + 64] = q1;

    __shared__ float r4[4];
    if (lane == 0) r4[wave] = dot * inv_i * inv_t;
    __syncthreads();
    if (threadIdx.x == 0)
        alignp[blockIdx.x] = r4[0] + r4[1] + r4[2] + r4[3];
}

// ---------------------------------------------------------------- gram + lme
// 128x128 tile per block, 4 waves in 2x2 (each wave 64x64 via 2x2 of 32x32
// MX-fp8 MFMA, K=64 per instruction). BK=128 bytes staged per iteration.
// LDS tile [128 rows][8 chunks of 16B], physical chunk = chunk ^ (row&7).
__global__ __launch_bounds__(256) void gram_kernel(
    const unsigned char* __restrict__ A0,   // fp8 [8192][512], blockIdx.y==0
    const unsigned char* __restrict__ A1,   // blockIdx.y==1
    float* __restrict__ S)                  // S[y*32 + x%32] += weighted sum
{
    // Decode upper-triangular tile index t -> (i, j), i <= j.
    const int t = blockIdx.x;
    int i = (int)((129.0f - sqrtf(129.0f * 129.0f - 8.0f * (float)t)) * 0.5f);
    while ((i + 1) * (129 - (i + 1)) / 2 <= t) ++i;
    while (i * (129 - i) / 2 > t) --i;
    const int j = i + (t - i * (129 - i) / 2);

    const unsigned char* __restrict__ A = blockIdx.y ? A1 : A0;
    const int tid  = threadIdx.x;
    const int lane = tid & 63;
    const int wave = tid >> 6;
    const int wm = wave & 1, wn = wave >> 1;   // 2x2 wave grid over 128x128
    const int lr = lane & 31;                  // row-in-subtile
    const int h  = lane >> 5;                  // K-half select

    const unsigned char* gA = A + (size_t)i * 128 * DBYTES;
    const unsigned char* gB = A + (size_t)j * 128 * DBYTES;

    __shared__ __align__(16) unsigned char ldsA[128 * 128];   // 16 KB
    __shared__ __align__(16) unsigned char ldsB[128 * 128];   // 16 KB

    float16v acc[2][2];
    #pragma unroll
    for (int a = 0; a < 2; ++a)
        #pragma unroll
        for (int b = 0; b < 2; ++b)
            #pragma unroll
            for (int r = 0; r < 16; ++r) acc[a][b][r] = 0.0f;

    for (int k0 = 0; k0 < DBYTES; k0 += 128) {
        // Stage 128x128B of A-rows and B-rows. 256 thr * 16 B * 4 rounds each.
        // LDS slot lane-contiguous (global_load_lds requirement); global chunk
        // is swizzled: c_log = c_phys ^ (r&7).
        #pragma unroll
        for (int rnd = 0; rnd < 4; ++rnd) {
            const int slot = rnd * 4096 + tid * 16;
            const int r    = slot >> 7;
            const int cp   = (slot >> 4) & 7;
            const int cl   = cp ^ (r & 7);
            load_lds16(gA + (size_t)r * DBYTES + k0 + cl * 16, &ldsA[slot]);
            load_lds16(gB + (size_t)r * DBYTES + k0 + cl * 16, &ldsB[slot]);
        }
        __syncthreads();

        #pragma unroll
        for (int kk = 0; kk < 2; ++kk) {       // two K=64 steps per stage
            const int cbase = kk * 4 + h * 2;  // logical 16B chunk, this lane
            int8v av[2], bv[2];
            #pragma unroll
            for (int mt = 0; mt < 2; ++mt) {
                const int r = wm * 64 + mt * 32 + lr;
                const int4v q0 = *(const int4v*)&ldsA[r * 128 + ((cbase    ) ^ (r & 7)) * 16];
                const int4v q1 = *(const int4v*)&ldsA[r * 128 + ((cbase + 1) ^ (r & 7)) * 16];
                av[mt][0]=q0[0]; av[mt][1]=q0[1]; av[mt][2]=q0[2]; av[mt][3]=q0[3];
                av[mt][4]=q1[0]; av[mt][5]=q1[1]; av[mt][6]=q1[2]; av[mt][7]=q1[3];
            }
            #pragma unroll
            for (int nt = 0; nt < 2; ++nt) {
                const int r = wn * 64 + nt * 32 + lr;
                const int4v q0 = *(const int4v*)&ldsB[r * 128 + ((cbase    ) ^ (r & 7)) * 16];
                const int4v q1 = *(const int4v*)&ldsB[r * 128 + ((cbase + 1) ^ (r & 7)) * 16];
                bv[nt][0]=q0[0]; bv[nt][1]=q0[1]; bv[nt][2]=q0[2]; bv[nt][3]=q0[3];
                bv[nt][4]=q1[0]; bv[nt][5]=q1[1]; bv[nt][6]=q1[2]; bv[nt][7]=q1[3];
            }
            #pragma unroll
            for (int mt = 0; mt < 2; ++mt)
                #pragma unroll
                for (int nt = 0; nt < 2; ++nt)
                    acc[mt][nt] = __builtin_amdgcn_mfma_scale_f32_32x32x64_f8f6f4(
                        av[mt], bv[nt], acc[mt][nt],
                        0, 0,                       // cbsz=fp8(e4m3), blgp=fp8
                        0, SCALE_SPLAT,             // opsel_a, scale_a (2^-10)
                        0, SCALE_SPLAT);            // opsel_b, scale_b (2^-10)
        }
        __syncthreads();
    }

    // Epilogue: sum exp(4*min(G,1)-4); tile-sum is layout-invariant.
    float s = 0.0f;
    #pragma unroll
    for (int mt = 0; mt < 2; ++mt)
        #pragma unroll
        for (int nt = 0; nt < 2; ++nt)
            #pragma unroll
            for (int r2 = 0; r2 < 16; ++r2) {
                const float g = acc[mt][nt][r2];
                s += __expf(4.0f * fminf(g, 1.0f) - 4.0f);
            }
    #pragma unroll
    for (int off = 32; off; off >>= 1) s += __shfl_down(s, off);
    __shared__ float ps[4];
    if (lane == 0) ps[wave] = s;
    __syncthreads();
    if (tid == 0) {
        const float tot = ps[0] + ps[1] + ps[2] + ps[3];
        const float w = (i == j) ? 1.0f : 2.0f;   // symmetry weight
        atomicAdd(&S[blockIdx.y * 32 + (blockIdx.x & 31)], tot * w);
    }
}

// ---------------------------------------------------------------- finalize
__global__ __launch_bounds__(256) void finalize_kernel(
    const float* __restrict__ S,       // [64]
    const float* __restrict__ alignp,  // [2048]
    float* __restrict__ out)
{
    const int tid = threadIdx.x;
    float a = 0.0f;
    #pragma unroll
    for (int k = 0; k < 8; ++k) a += alignp[tid + 256 * k];
    #pragma unroll
    for (int off = 32; off; off >>= 1) a += __shfl_down(a, off);
    __shared__ float r4[4];
    if ((tid & 63) == 0) r4[tid >> 6] = a;
    __syncthreads();
    if (tid == 0) {
        const double A = (double)r4[0] + r4[1] + r4[2] + r4[3];
        double si = 0.0, st = 0.0;
        for (int k = 0; k < 32; ++k) { si += S[k]; st += S[32 + k]; }
        const double align = 2.0 - 2.0 * A / (double)NROWS;
        const double n2 = (double)NROWS * (double)NROWS;
        const double unif = 0.5 * (log(si / n2) + log(st / n2));
        out[0] = (float)(3.0 * align + unif);
    }
}

// ---------------------------------------------------------------- launch
extern "C" void kernel_launch(void* const* d_in, const int* in_sizes, int n_in,
                              void* d_out, int out_size, void* d_ws, size_t ws_size,
                              hipStream_t stream) {
    const float* img = (const float*)d_in[0];
    const float* txt = (const float*)d_in[1];
    char* ws = (char*)d_ws;
    unsigned char* nimg = (unsigned char*)ws;                          // 4 MB
    unsigned char* ntxt = (unsigned char*)(ws + (size_t)NROWS * DBYTES);  // 4 MB
    float* S      = (float*)(ws + 2 * (size_t)NROWS * DBYTES);         // 64 floats
    float* alignp = S + 64;                                            // 2048 floats

    hipMemsetAsync(S, 0, 64 * sizeof(float), stream);
    normalize_kernel<<<NROWS / 4, 256, 0, stream>>>(img, txt, nimg, ntxt, alignp);
    dim3 grid(NTILES, 2);
    gram_kernel<<<grid, 256, 0, stream>>>(nimg, ntxt, S);
    finalize_kernel<<<1, 256, 0, stream>>>(S, alignp, (float*)d_out);
}